// Round 10
// baseline (1770.441 us; speedup 1.0000x reference)
//
#include <hip/hip_runtime.h>
#include <hip/hip_cooperative_groups.h>
#include <math.h>

namespace cg = cooperative_groups;

namespace {

constexpr int N = 100000;   // nodes
constexpr int E = 1600000;  // edges
constexpr int G = 2000;     // graphs
constexpr int L = 2000;     // links

constexpr int SCAN_CHUNK = 1024;
constexpr int NB = (N + SCAN_CHUNK - 1) / SCAN_CHUNK;  // 98

constexpr int NXCD = 8;
constexpr int NP = N / NXCD;  // 12500

// bf16 helpers (RNE pack, exact unpack)
__device__ __forceinline__ float bf2f(unsigned short u) {
  union { unsigned int i; float f; } v;
  v.i = ((unsigned int)u) << 16;
  return v.f;
}
__device__ __forceinline__ unsigned short f2bf(float f) {
  union { float f; unsigned int i; } v;
  v.f = f;
  const unsigned int x = v.i;
  return (unsigned short)((x + 0x7FFFu + ((x >> 16) & 1u)) >> 16);
}

struct Params {
  const float* x;
  const int* src; const int* dst; const int* batch; const int* link;
  const float* W[4]; const float* b[4]; const float* Wr[4]; const float* br[4];
  const float* g[4]; const float* bt[4];
  const float* Wm1; const float* bm1; const float* Wm2; const float* bm2;
  const float* Wm3; const float* bm3;
  float* out;
  int* deg; int* row_ptr; int* cursor; float* dis;
  int* bsum; int* boff; int* col;
  unsigned short* hdb;  // N*64 bf16 (gathered operand)
  float* r;             // N*64 fp32 (residual)
  float* io;            // N*64 fp32 (layer output / next input)
  float* gemb; float* cnt;
};

// ---- dual GEMM phase: hdb = bf16((xin@W)*dis[row]), r = xin@Wr ----
// Weights read from global (L1/L2 broadcast) so LDS never limits co-residency.
template <int FI, int FO>
__device__ void gemm_phase(const float* __restrict__ xin, const float* __restrict__ W,
                           const float* __restrict__ Wr, const float* __restrict__ dis,
                           unsigned short* __restrict__ hdb, float* __restrict__ r,
                           int gtid, int gsz) {
  constexpr int CG = FO / 4;
  const int total = (N / 4) * CG;
  for (int idx = gtid; idx < total; idx += gsz) {
    const int rb = idx / CG;
    const int colq = (idx - rb * CG) * 4;
    const int row0 = rb * 4;
    float4 aH[4], aR[4];
#pragma unroll
    for (int i = 0; i < 4; ++i) {
      aH[i] = make_float4(0.f, 0.f, 0.f, 0.f);
      aR[i] = make_float4(0.f, 0.f, 0.f, 0.f);
    }
    const float* xr = xin + (size_t)row0 * FI;
#pragma unroll
    for (int k = 0; k < FI; k += 4) {
      float xs[4][4];
#pragma unroll
      for (int i = 0; i < 4; ++i) {
        const float4 xv = *reinterpret_cast<const float4*>(xr + i * FI + k);
        xs[i][0] = xv.x; xs[i][1] = xv.y; xs[i][2] = xv.z; xs[i][3] = xv.w;
      }
#pragma unroll
      for (int kk = 0; kk < 4; ++kk) {
        const float4 w4 = *reinterpret_cast<const float4*>(&W[(k + kk) * FO + colq]);
        const float4 w4r = *reinterpret_cast<const float4*>(&Wr[(k + kk) * FO + colq]);
#pragma unroll
        for (int i = 0; i < 4; ++i) {
          aH[i].x = fmaf(xs[i][kk], w4.x, aH[i].x);
          aH[i].y = fmaf(xs[i][kk], w4.y, aH[i].y);
          aH[i].z = fmaf(xs[i][kk], w4.z, aH[i].z);
          aH[i].w = fmaf(xs[i][kk], w4.w, aH[i].w);
          aR[i].x = fmaf(xs[i][kk], w4r.x, aR[i].x);
          aR[i].y = fmaf(xs[i][kk], w4r.y, aR[i].y);
          aR[i].z = fmaf(xs[i][kk], w4r.z, aR[i].z);
          aR[i].w = fmaf(xs[i][kk], w4r.w, aR[i].w);
        }
      }
    }
    const float4 dv = *reinterpret_cast<const float4*>(dis + row0);
    const float dl[4] = {dv.x, dv.y, dv.z, dv.w};
#pragma unroll
    for (int i = 0; i < 4; ++i) {
      ushort4 ob;
      ob.x = f2bf(aH[i].x * dl[i]);
      ob.y = f2bf(aH[i].y * dl[i]);
      ob.z = f2bf(aH[i].z * dl[i]);
      ob.w = f2bf(aH[i].w * dl[i]);
      *reinterpret_cast<ushort4*>(&hdb[(size_t)(row0 + i) * FO + colq]) = ob;
      *reinterpret_cast<float4*>(&r[(size_t)(row0 + i) * FO + colq]) = aR[i];
    }
  }
}

// ---- fused CSR gather + self-loop + residual + LN + ReLU phase ----
// 1 node per FO-lane subgroup; bf16 scalar gathers; 8-way unroll (deg~16 -> 2 iters).
template <int FO, bool POOL>
__device__ void agg_phase(const int* __restrict__ row_ptr, const int* __restrict__ col,
                          const unsigned short* __restrict__ hdb, const float* __restrict__ r,
                          const float* __restrict__ dis,
                          const float* __restrict__ b, const float* __restrict__ br,
                          const float* __restrict__ g, const float* __restrict__ bt,
                          float* __restrict__ out, const int* __restrict__ batch,
                          float* __restrict__ gemb, float* __restrict__ cnt,
                          int gtid, int gsz) {
  constexpr int NPW = 64 / FO;
  const int lane = gtid & 63;
  const int f = lane & (FO - 1);
  const int sub = lane / FO;
  const int waveId = gtid >> 6;
  const int nWaves = gsz >> 6;
  const int nGroups = N / NPW;
  const float bf = b[f], brf = br[f], gf = g[f], btf = bt[f];
  for (int w = waveId; w < nGroups; w += nWaves) {
    const int node = w * NPW + sub;
    const int beg = row_ptr[node];
    const int end = row_ptr[node + 1];
    float a0 = 0.f, a1 = 0.f, a2 = 0.f, a3 = 0.f, a4 = 0.f, a5 = 0.f, a6 = 0.f, a7 = 0.f;
    int k = beg;
    const int end8 = beg + ((end - beg) & ~7);
    for (; k < end8; k += 8) {
      const int s0 = col[k];
      const int s1 = col[k + 1];
      const int s2 = col[k + 2];
      const int s3 = col[k + 3];
      const int s4 = col[k + 4];
      const int s5 = col[k + 5];
      const int s6 = col[k + 6];
      const int s7 = col[k + 7];
      a0 += bf2f(hdb[(size_t)s0 * FO + f]);
      a1 += bf2f(hdb[(size_t)s1 * FO + f]);
      a2 += bf2f(hdb[(size_t)s2 * FO + f]);
      a3 += bf2f(hdb[(size_t)s3 * FO + f]);
      a4 += bf2f(hdb[(size_t)s4 * FO + f]);
      a5 += bf2f(hdb[(size_t)s5 * FO + f]);
      a6 += bf2f(hdb[(size_t)s6 * FO + f]);
      a7 += bf2f(hdb[(size_t)s7 * FO + f]);
    }
    for (; k < end; ++k) a0 += bf2f(hdb[(size_t)col[k] * FO + f]);
    const float acc = ((a0 + a1) + (a2 + a3)) + ((a4 + a5) + (a6 + a7));
    const float dv = dis[node];
    const size_t base = (size_t)node * FO + f;
    const float v = fmaf(dv, acc + bf2f(hdb[base]), bf + r[base] + brf);
    float s = v;
#pragma unroll
    for (int m = FO / 2; m >= 1; m >>= 1) s += __shfl_xor(s, m, 64);
    const float mean = s * (1.0f / FO);
    const float d0 = v - mean;
    float vs = d0 * d0;
#pragma unroll
    for (int m = FO / 2; m >= 1; m >>= 1) vs += __shfl_xor(vs, m, 64);
    const float var = vs * (1.0f / FO);
    float o = d0 * rsqrtf(var + 1e-5f) * gf + btf;
    o = fmaxf(o, 0.f);
    if (POOL) {
      const int bb = batch[node];
      atomicAdd(&gemb[bb * FO + f], o);
      if (f == 0) atomicAdd(&cnt[bb], 1.0f);
    } else {
      out[base] = o;
    }
  }
}

// ---- the single fused cooperative kernel ----
__global__ __launch_bounds__(256, 4) void fused_kernel(Params p) {
  cg::grid_group grid = cg::this_grid();
  const int tid = threadIdx.x;
  const int bid = blockIdx.x;
  const int gtid = bid * blockDim.x + tid;
  const int gsz = gridDim.x * blockDim.x;

  // Phase A: zero deg, gemb, cnt (replaces memsets)
  for (int i = gtid; i < N; i += gsz) p.deg[i] = 0;
  for (int i = gtid; i < G * 16; i += gsz) p.gemb[i] = 0.f;
  for (int i = gtid; i < G; i += gsz) p.cnt[i] = 0.f;
  grid.sync();

  // Phase B: hist (XCD-partitioned: partition = bid&7)
  {
    const int part = bid & (NXCD - 1);
    const int lo = part * NP;
    const int hi = lo + NP;
    const int bidp = bid >> 3;
    const int stridev = (gridDim.x >> 3) * blockDim.x;
    const int nvec = E >> 2;
    for (int v = bidp * blockDim.x + tid; v < nvec; v += stridev) {
      const int4 d4 = *reinterpret_cast<const int4*>(p.dst + v * 4);
      if (d4.x >= lo && d4.x < hi) atomicAdd(&p.deg[d4.x], 1);
      if (d4.y >= lo && d4.y < hi) atomicAdd(&p.deg[d4.y], 1);
      if (d4.z >= lo && d4.z < hi) atomicAdd(&p.deg[d4.z], 1);
      if (d4.w >= lo && d4.w < hi) atomicAdd(&p.deg[d4.w], 1);
    }
  }
  grid.sync();

  // Phase C: scan1 — per-chunk sums (blocks 0..NB-1)
  {
    __shared__ int ss1[256];
    if (bid < NB) {
      const int base = bid * SCAN_CHUNK + tid * 4;
      int s = 0;
      if (base < N) {
        const int4 v = *reinterpret_cast<const int4*>(p.deg + base);
        s = v.x + v.y + v.z + v.w;
      }
      ss1[tid] = s;
      __syncthreads();
#pragma unroll
      for (int off = 128; off >= 1; off >>= 1) {
        if (tid < off) ss1[tid] += ss1[tid + off];
        __syncthreads();
      }
      if (tid == 0) p.bsum[bid] = ss1[0];
    }
  }
  grid.sync();

  // Phase D: scan2 — exclusive scan of NB block sums (block 0, 256 threads)
  {
    __shared__ int ss2[256];
    if (bid == 0) {
      ss2[tid] = (tid < NB) ? p.bsum[tid] : 0;
      __syncthreads();
#pragma unroll
      for (int off = 1; off < 256; off <<= 1) {
        const int v = (tid >= off) ? ss2[tid - off] : 0;
        __syncthreads();
        ss2[tid] += v;
        __syncthreads();
      }
      if (tid < NB) p.boff[tid] = (tid == 0) ? 0 : ss2[tid - 1];
    }
  }
  grid.sync();

  // Phase E: scan3 — local scan + offset -> row_ptr & cursor; dis = rsqrt(deg+1)
  {
    __shared__ int ss3[256];
    if (bid < NB) {
      const int base = bid * SCAN_CHUNK + tid * 4;
      int d0 = 0, d1 = 0, d2 = 0, d3 = 0;
      if (base < N) {
        const int4 v = *reinterpret_cast<const int4*>(p.deg + base);
        d0 = v.x; d1 = v.y; d2 = v.z; d3 = v.w;
      }
      ss3[tid] = d0 + d1 + d2 + d3;
      __syncthreads();
#pragma unroll
      for (int off = 1; off < 256; off <<= 1) {
        const int v = (tid >= off) ? ss3[tid - off] : 0;
        __syncthreads();
        ss3[tid] += v;
        __syncthreads();
      }
      if (base < N) {
        const int p0 = ((tid == 0) ? 0 : ss3[tid - 1]) + p.boff[bid];
        const int p1 = p0 + d0;
        const int p2 = p1 + d1;
        const int p3 = p2 + d2;
        *reinterpret_cast<int4*>(p.row_ptr + base) = make_int4(p0, p1, p2, p3);
        *reinterpret_cast<int4*>(p.cursor + base) = make_int4(p0, p1, p2, p3);
        const float4 dv = make_float4(rsqrtf((float)d0 + 1.0f), rsqrtf((float)d1 + 1.0f),
                                      rsqrtf((float)d2 + 1.0f), rsqrtf((float)d3 + 1.0f));
        *reinterpret_cast<float4*>(p.dis + base) = dv;
      }
      if (bid == 0 && tid == 0) p.row_ptr[N] = E;
    }
  }
  grid.sync();

  // Phase F: fill (XCD-partitioned)
  {
    const int part = bid & (NXCD - 1);
    const int lo = part * NP;
    const int hi = lo + NP;
    const int bidp = bid >> 3;
    const int stridev = (gridDim.x >> 3) * blockDim.x;
    const int nvec = E >> 2;
    for (int v = bidp * blockDim.x + tid; v < nvec; v += stridev) {
      const int e = v * 4;
      const int4 d4 = *reinterpret_cast<const int4*>(p.dst + e);
      if (d4.x >= lo && d4.x < hi) p.col[atomicAdd(&p.cursor[d4.x], 1)] = p.src[e];
      if (d4.y >= lo && d4.y < hi) p.col[atomicAdd(&p.cursor[d4.y], 1)] = p.src[e + 1];
      if (d4.z >= lo && d4.z < hi) p.col[atomicAdd(&p.cursor[d4.z], 1)] = p.src[e + 2];
      if (d4.w >= lo && d4.w < hi) p.col[atomicAdd(&p.cursor[d4.w], 1)] = p.src[e + 3];
    }
  }
  grid.sync();

  // Layer 1: 128 -> 64
  gemm_phase<128, 64>(p.x, p.W[0], p.Wr[0], p.dis, p.hdb, p.r, gtid, gsz);
  grid.sync();
  agg_phase<64, false>(p.row_ptr, p.col, p.hdb, p.r, p.dis, p.b[0], p.br[0], p.g[0], p.bt[0],
                       p.io, p.batch, p.gemb, p.cnt, gtid, gsz);
  grid.sync();
  // Layer 2: 64 -> 32
  gemm_phase<64, 32>(p.io, p.W[1], p.Wr[1], p.dis, p.hdb, p.r, gtid, gsz);
  grid.sync();
  agg_phase<32, false>(p.row_ptr, p.col, p.hdb, p.r, p.dis, p.b[1], p.br[1], p.g[1], p.bt[1],
                       p.io, p.batch, p.gemb, p.cnt, gtid, gsz);
  grid.sync();
  // Layer 3: 32 -> 16
  gemm_phase<32, 16>(p.io, p.W[2], p.Wr[2], p.dis, p.hdb, p.r, gtid, gsz);
  grid.sync();
  agg_phase<16, false>(p.row_ptr, p.col, p.hdb, p.r, p.dis, p.b[2], p.br[2], p.g[2], p.bt[2],
                       p.io, p.batch, p.gemb, p.cnt, gtid, gsz);
  grid.sync();
  // Layer 4: 16 -> 16 (pool fused into agg epilogue)
  gemm_phase<16, 16>(p.io, p.W[3], p.Wr[3], p.dis, p.hdb, p.r, gtid, gsz);
  grid.sync();
  agg_phase<16, true>(p.row_ptr, p.col, p.hdb, p.r, p.dis, p.b[3], p.br[3], p.g[3], p.bt[3],
                      nullptr, p.batch, p.gemb, p.cnt, gtid, gsz);
  grid.sync();

  // Phase Z: link MLP (gdiv folded in: divide gemb rows by cnt on load)
  if (gtid < L) {
    const int a = p.link[gtid];
    const int c = p.link[L + gtid];
    const float ia = 1.0f / fmaxf(p.cnt[a], 1.0f);
    const float ic = 1.0f / fmaxf(p.cnt[c], 1.0f);
    float feat[32];
#pragma unroll
    for (int k = 0; k < 16; ++k) feat[k] = p.gemb[a * 16 + k] * ia;
#pragma unroll
    for (int k = 0; k < 16; ++k) feat[16 + k] = p.gemb[c * 16 + k] * ic;
    float z1[16];
#pragma unroll
    for (int j = 0; j < 16; ++j) {
      float s = p.bm1[j];
#pragma unroll
      for (int k = 0; k < 32; ++k) s = fmaf(feat[k], p.Wm1[k * 16 + j], s);
      z1[j] = fmaxf(s, 0.f);
    }
    float z2[8];
#pragma unroll
    for (int j = 0; j < 8; ++j) {
      float s = p.bm2[j];
#pragma unroll
      for (int k = 0; k < 16; ++k) s = fmaf(z1[k], p.Wm2[k * 8 + j], s);
      z2[j] = fmaxf(s, 0.f);
    }
    float z3 = p.bm3[0];
#pragma unroll
    for (int k = 0; k < 8; ++k) z3 = fmaf(z2[k], p.Wm3[k], z3);
    p.out[gtid] = 1.f / (1.f + expf(-z3));
  }
}

}  // namespace

extern "C" void kernel_launch(void* const* d_in, const int* in_sizes, int n_in,
                              void* d_out, int out_size, void* d_ws, size_t ws_size,
                              hipStream_t stream) {
  (void)in_sizes; (void)n_in; (void)out_size; (void)ws_size;
  Params p;
  p.x = (const float*)d_in[0];
  p.src = (const int*)d_in[1];
  p.dst = (const int*)d_in[2];
  p.batch = (const int*)d_in[3];
  p.link = (const int*)d_in[4];
  for (int i = 0; i < 4; ++i) {
    p.W[i] = (const float*)d_in[5 + 6 * i + 0];
    p.b[i] = (const float*)d_in[5 + 6 * i + 1];
    p.Wr[i] = (const float*)d_in[5 + 6 * i + 2];
    p.br[i] = (const float*)d_in[5 + 6 * i + 3];
    p.g[i] = (const float*)d_in[5 + 6 * i + 4];
    p.bt[i] = (const float*)d_in[5 + 6 * i + 5];
  }
  p.Wm1 = (const float*)d_in[29];
  p.bm1 = (const float*)d_in[30];
  p.Wm2 = (const float*)d_in[31];
  p.bm2 = (const float*)d_in[32];
  p.Wm3 = (const float*)d_in[33];
  p.bm3 = (const float*)d_in[34];
  p.out = (float*)d_out;

  // workspace layout (4B units unless noted):
  char* wsb = (char*)d_ws;
  p.deg = (int*)wsb;                                  // N
  p.row_ptr = p.deg + N;                              // N+1
  p.cursor = p.row_ptr + (N + 1);                     // N
  p.dis = (float*)(p.cursor + N);                     // N
  p.bsum = (int*)(p.dis + N);                         // NB
  p.boff = p.bsum + NB;                               // NB
  p.col = p.boff + NB;                                // E
  p.hdb = (unsigned short*)(p.col + E);               // N*64 bf16
  p.r = (float*)(p.hdb + (size_t)N * 64);             // N*64
  p.io = p.r + (size_t)N * 64;                        // N*64
  p.gemb = p.io + (size_t)N * 64;                     // G*16
  p.cnt = p.gemb + (size_t)G * 16;                    // G

  // Size the cooperative grid to guaranteed co-residency.
  int maxBlocksPerCU = 0;
  hipOccupancyMaxActiveBlocksPerMultiprocessor(&maxBlocksPerCU, fused_kernel, 256, 0);
  if (maxBlocksPerCU <= 0) maxBlocksPerCU = 3;  // conservative fallback
  long long blocks = (long long)maxBlocksPerCU * 256;  // 256 CUs on MI355X
  if (blocks > 1024) blocks = 1024;
  blocks &= ~7LL;               // partition logic needs gridDim % 8 == 0
  if (blocks < 104) blocks = 104;  // scans need >= NB(98) blocks

  void* args[] = {&p};
  hipLaunchCooperativeKernel((void*)fused_kernel, dim3((unsigned)blocks), dim3(256), args, 0,
                             stream);
}

// Round 11
// 732.235 us; speedup vs baseline: 2.4179x; 2.4179x over previous
//
#include <hip/hip_runtime.h>
#include <hip/hip_cooperative_groups.h>
#include <math.h>

namespace cg = cooperative_groups;

namespace {

constexpr int N = 100000;   // nodes
constexpr int E = 1600000;  // edges
constexpr int G = 2000;     // graphs
constexpr int L = 2000;     // links

constexpr int SCAN_CHUNK = 1024;
constexpr int NB = (N + SCAN_CHUNK - 1) / SCAN_CHUNK;  // 98

constexpr int NXCD = 8;
constexpr int NP = N / NXCD;  // 12500

// bf16 helpers (RNE pack, exact unpack)
__device__ __forceinline__ float bf2f(unsigned short u) {
  union { unsigned int i; float f; } v;
  v.i = ((unsigned int)u) << 16;
  return v.f;
}
__device__ __forceinline__ unsigned short f2bf(float f) {
  union { float f; unsigned int i; } v;
  v.f = f;
  const unsigned int x = v.i;
  return (unsigned short)((x + 0x7FFFu + ((x >> 16) & 1u)) >> 16);
}

// ---------------- CSR build (XCD-partitioned hist/fill) ----------------

__global__ void hist_part_kernel(const int* __restrict__ dst, int* __restrict__ deg) {
  const int part = blockIdx.x & (NXCD - 1);
  const int lo = part * NP;
  const int hi = lo + NP;
  const int bidp = blockIdx.x >> 3;
  const int stridev = (gridDim.x >> 3) * blockDim.x;
  const int nvec = E >> 2;
  for (int v = bidp * blockDim.x + threadIdx.x; v < nvec; v += stridev) {
    const int4 d4 = *reinterpret_cast<const int4*>(dst + v * 4);
    if (d4.x >= lo && d4.x < hi) atomicAdd(&deg[d4.x], 1);
    if (d4.y >= lo && d4.y < hi) atomicAdd(&deg[d4.y], 1);
    if (d4.z >= lo && d4.z < hi) atomicAdd(&deg[d4.z], 1);
    if (d4.w >= lo && d4.w < hi) atomicAdd(&deg[d4.w], 1);
  }
}

__global__ void fill_part_kernel(const int* __restrict__ src, const int* __restrict__ dst,
                                 int* __restrict__ cursor, int* __restrict__ col) {
  const int part = blockIdx.x & (NXCD - 1);
  const int lo = part * NP;
  const int hi = lo + NP;
  const int bidp = blockIdx.x >> 3;
  const int stridev = (gridDim.x >> 3) * blockDim.x;
  const int nvec = E >> 2;
  for (int v = bidp * blockDim.x + threadIdx.x; v < nvec; v += stridev) {
    const int e = v * 4;
    const int4 d4 = *reinterpret_cast<const int4*>(dst + e);
    if (d4.x >= lo && d4.x < hi) col[atomicAdd(&cursor[d4.x], 1)] = src[e];
    if (d4.y >= lo && d4.y < hi) col[atomicAdd(&cursor[d4.y], 1)] = src[e + 1];
    if (d4.z >= lo && d4.z < hi) col[atomicAdd(&cursor[d4.z], 1)] = src[e + 2];
    if (d4.w >= lo && d4.w < hi) col[atomicAdd(&cursor[d4.w], 1)] = src[e + 3];
  }
}

// 3-pass scan fused into one cooperative kernel (98 blocks, trivially co-resident).
__global__ __launch_bounds__(256) void scan_fused_kernel(const int* __restrict__ deg,
                                                         int* __restrict__ bsum,
                                                         int* __restrict__ boff,
                                                         int* __restrict__ row_ptr,
                                                         int* __restrict__ cursor,
                                                         float* __restrict__ dis) {
  cg::grid_group grid = cg::this_grid();
  const int tid = threadIdx.x;
  const int bid = blockIdx.x;
  const int base = bid * SCAN_CHUNK + tid * 4;
  __shared__ int ss[256];

  // pass 1: per-chunk sums
  int d0 = 0, d1 = 0, d2 = 0, d3 = 0;
  if (base < N) {
    const int4 v = *reinterpret_cast<const int4*>(deg + base);
    d0 = v.x; d1 = v.y; d2 = v.z; d3 = v.w;
  }
  ss[tid] = d0 + d1 + d2 + d3;
  __syncthreads();
#pragma unroll
  for (int off = 128; off >= 1; off >>= 1) {
    if (tid < off) ss[tid] += ss[tid + off];
    __syncthreads();
  }
  if (tid == 0) bsum[bid] = ss[0];
  grid.sync();

  // pass 2: exclusive scan of block sums (block 0)
  if (bid == 0) {
    __shared__ int s2[256];
    s2[tid] = (tid < NB) ? bsum[tid] : 0;
    __syncthreads();
#pragma unroll
    for (int off = 1; off < 256; off <<= 1) {
      const int v = (tid >= off) ? s2[tid - off] : 0;
      __syncthreads();
      s2[tid] += v;
      __syncthreads();
    }
    if (tid < NB) boff[tid] = (tid == 0) ? 0 : s2[tid - 1];
  }
  grid.sync();

  // pass 3: local exclusive scan + offset; dis = rsqrt(deg+1)
  __syncthreads();
  ss[tid] = d0 + d1 + d2 + d3;
  __syncthreads();
#pragma unroll
  for (int off = 1; off < 256; off <<= 1) {
    const int v = (tid >= off) ? ss[tid - off] : 0;
    __syncthreads();
    ss[tid] += v;
    __syncthreads();
  }
  if (base < N) {
    const int p0 = ((tid == 0) ? 0 : ss[tid - 1]) + boff[bid];
    const int p1 = p0 + d0;
    const int p2 = p1 + d1;
    const int p3 = p2 + d2;
    *reinterpret_cast<int4*>(row_ptr + base) = make_int4(p0, p1, p2, p3);
    *reinterpret_cast<int4*>(cursor + base) = make_int4(p0, p1, p2, p3);
    const float4 dv = make_float4(rsqrtf((float)d0 + 1.0f), rsqrtf((float)d1 + 1.0f),
                                  rsqrtf((float)d2 + 1.0f), rsqrtf((float)d3 + 1.0f));
    *reinterpret_cast<float4*>(dis + base) = dv;
  }
  if (bid == 0 && tid == 0) row_ptr[N] = E;
}

// ---------------- dual GEMM: hdb = bf16((x@W)*dis[row]), r = x@Wr ----------------
// ZERO_POOL: fold gemb/cnt zeroing into the layer-4 GEMM (completes before agg4 pools).

__device__ __forceinline__ void f4fma(float4& a, float s, const float4 w) {
  a.x = fmaf(s, w.x, a.x);
  a.y = fmaf(s, w.y, a.y);
  a.z = fmaf(s, w.z, a.z);
  a.w = fmaf(s, w.w, a.w);
}

template <int FI, int FO, bool ZERO_POOL>
__global__ __launch_bounds__(1024) void gemm2_kernel(const float* __restrict__ x,
                                                     const float* __restrict__ W,
                                                     const float* __restrict__ Wr,
                                                     const float* __restrict__ dis,
                                                     unsigned short* __restrict__ hdb,
                                                     float* __restrict__ r,
                                                     float* __restrict__ gemb_cnt) {
  __shared__ float sW[FI * FO];
  __shared__ float sWr[FI * FO];
  for (int i = threadIdx.x; i < FI * FO; i += blockDim.x) {
    sW[i] = W[i];
    sWr[i] = Wr[i];
  }
  if (ZERO_POOL) {
    const int gstride = gridDim.x * blockDim.x;
    for (int i = blockIdx.x * blockDim.x + threadIdx.x; i < G * 16 + G; i += gstride)
      gemb_cnt[i] = 0.f;
  }
  __syncthreads();
  constexpr int CG = FO / 4;            // col groups
  const int total = (N / 4) * CG;       // N % 4 == 0
  const int stride = gridDim.x * blockDim.x;
  for (int idx = blockIdx.x * blockDim.x + threadIdx.x; idx < total; idx += stride) {
    const int rb = idx / CG;
    const int col = (idx - rb * CG) * 4;
    const int row0 = rb * 4;
    float4 aH[4], aR[4];
#pragma unroll
    for (int i = 0; i < 4; ++i) {
      aH[i] = make_float4(0.f, 0.f, 0.f, 0.f);
      aR[i] = make_float4(0.f, 0.f, 0.f, 0.f);
    }
    const float* xr = x + (size_t)row0 * FI;
#pragma unroll
    for (int k = 0; k < FI; k += 4) {
      float xs[4][4];
#pragma unroll
      for (int i = 0; i < 4; ++i) {
        const float4 xv = *reinterpret_cast<const float4*>(xr + i * FI + k);
        xs[i][0] = xv.x; xs[i][1] = xv.y; xs[i][2] = xv.z; xs[i][3] = xv.w;
      }
#pragma unroll
      for (int kk = 0; kk < 4; ++kk) {
        const float4 w4 = *reinterpret_cast<const float4*>(&sW[(k + kk) * FO + col]);
        const float4 w4r = *reinterpret_cast<const float4*>(&sWr[(k + kk) * FO + col]);
#pragma unroll
        for (int i = 0; i < 4; ++i) {
          f4fma(aH[i], xs[i][kk], w4);
          f4fma(aR[i], xs[i][kk], w4r);
        }
      }
    }
    const float4 dv = *reinterpret_cast<const float4*>(dis + row0);
    const float dl[4] = {dv.x, dv.y, dv.z, dv.w};
#pragma unroll
    for (int i = 0; i < 4; ++i) {
      ushort4 ob;
      ob.x = f2bf(aH[i].x * dl[i]);
      ob.y = f2bf(aH[i].y * dl[i]);
      ob.z = f2bf(aH[i].z * dl[i]);
      ob.w = f2bf(aH[i].w * dl[i]);
      *reinterpret_cast<ushort4*>(&hdb[(size_t)(row0 + i) * FO + col]) = ob;
      *reinterpret_cast<float4*>(&r[(size_t)(row0 + i) * FO + col]) = aR[i];
    }
  }
}

// ---------------- fused CSR gather + self-loop + residual + LN + ReLU ----------------
// 1 node per FO-lane subgroup; bf16 scalar gathers; 8-way PREDICATED unroll:
// clamped-index loads keep 8 gathers in flight even in the tail (no serial remainder).

template <int FO, bool POOL>
__global__ void gcn_agg_kernel(const int* __restrict__ row_ptr, const int* __restrict__ col,
                               const unsigned short* __restrict__ hdb, const float* __restrict__ r,
                               const float* __restrict__ dis,
                               const float* __restrict__ b, const float* __restrict__ br,
                               const float* __restrict__ g, const float* __restrict__ bt,
                               float* __restrict__ out, const int* __restrict__ batch,
                               float* __restrict__ gemb, float* __restrict__ cnt) {
  constexpr int NPW = 64 / FO;  // nodes per wave (N % NPW == 0)
  const int lane = threadIdx.x & 63;
  const int f = lane & (FO - 1);
  const int sub = lane / FO;
  const int waveId = (blockIdx.x * blockDim.x + threadIdx.x) >> 6;
  const int nWaves = (gridDim.x * blockDim.x) >> 6;
  const int nGroups = N / NPW;
  const float bf = b[f], brf = br[f], gf = g[f], btf = bt[f];
  for (int w = waveId; w < nGroups; w += nWaves) {
    const int node = w * NPW + sub;
    const int beg = row_ptr[node];
    const int end = row_ptr[node + 1];
    float a0 = 0.f, a1 = 0.f, a2 = 0.f, a3 = 0.f, a4 = 0.f, a5 = 0.f, a6 = 0.f, a7 = 0.f;
    for (int k = beg; k < end; k += 8) {
      const int e1 = end - 1;
      const int k0 = k, k1 = min(k + 1, e1), k2 = min(k + 2, e1), k3 = min(k + 3, e1);
      const int k4 = min(k + 4, e1), k5 = min(k + 5, e1), k6 = min(k + 6, e1), k7 = min(k + 7, e1);
      const int s0 = col[k0], s1 = col[k1], s2 = col[k2], s3 = col[k3];
      const int s4 = col[k4], s5 = col[k5], s6 = col[k6], s7 = col[k7];
      const float v0 = bf2f(hdb[(size_t)s0 * FO + f]);
      const float v1 = bf2f(hdb[(size_t)s1 * FO + f]);
      const float v2 = bf2f(hdb[(size_t)s2 * FO + f]);
      const float v3 = bf2f(hdb[(size_t)s3 * FO + f]);
      const float v4 = bf2f(hdb[(size_t)s4 * FO + f]);
      const float v5 = bf2f(hdb[(size_t)s5 * FO + f]);
      const float v6 = bf2f(hdb[(size_t)s6 * FO + f]);
      const float v7 = bf2f(hdb[(size_t)s7 * FO + f]);
      a0 += v0;                              // k0 always valid
      a1 += (k + 1 < end) ? v1 : 0.f;
      a2 += (k + 2 < end) ? v2 : 0.f;
      a3 += (k + 3 < end) ? v3 : 0.f;
      a4 += (k + 4 < end) ? v4 : 0.f;
      a5 += (k + 5 < end) ? v5 : 0.f;
      a6 += (k + 6 < end) ? v6 : 0.f;
      a7 += (k + 7 < end) ? v7 : 0.f;
    }
    const float acc = ((a0 + a1) + (a2 + a3)) + ((a4 + a5) + (a6 + a7));
    const float dv = dis[node];
    const size_t base = (size_t)node * FO + f;
    const float v = fmaf(dv, acc + bf2f(hdb[base]), bf + r[base] + brf);
    float s = v;
#pragma unroll
    for (int m = FO / 2; m >= 1; m >>= 1) s += __shfl_xor(s, m, 64);
    const float mean = s * (1.0f / FO);
    const float d0 = v - mean;
    float vs = d0 * d0;
#pragma unroll
    for (int m = FO / 2; m >= 1; m >>= 1) vs += __shfl_xor(vs, m, 64);
    const float var = vs * (1.0f / FO);
    float o = d0 * rsqrtf(var + 1e-5f) * gf + btf;
    o = fmaxf(o, 0.f);
    if (POOL) {
      const int bb = batch[node];
      atomicAdd(&gemb[bb * FO + f], o);
      if (f == 0) atomicAdd(&cnt[bb], 1.0f);
    } else {
      out[base] = o;
    }
  }
}

// ---------------- link MLP (pool-normalize folded in) ----------------

__global__ void mlp_kernel(const float* __restrict__ gemb, const float* __restrict__ cnt,
                           const int* __restrict__ link,
                           const float* __restrict__ Wm1, const float* __restrict__ bm1,
                           const float* __restrict__ Wm2, const float* __restrict__ bm2,
                           const float* __restrict__ Wm3, const float* __restrict__ bm3,
                           float* __restrict__ out) {
  __shared__ float sW1[32 * 16], sW2[16 * 8], sW3[8], sb1[16], sb2[8], sb3;
  for (int i = threadIdx.x; i < 32 * 16; i += blockDim.x) sW1[i] = Wm1[i];
  for (int i = threadIdx.x; i < 16 * 8; i += blockDim.x) sW2[i] = Wm2[i];
  if (threadIdx.x < 8) {
    sW3[threadIdx.x] = Wm3[threadIdx.x];
    sb2[threadIdx.x] = bm2[threadIdx.x];
  }
  if (threadIdx.x < 16) sb1[threadIdx.x] = bm1[threadIdx.x];
  if (threadIdx.x == 0) sb3 = bm3[0];
  __syncthreads();
  const int l = blockIdx.x * blockDim.x + threadIdx.x;
  if (l >= L) return;
  const int a = link[l];
  const int c = link[L + l];
  const float ia = 1.0f / fmaxf(cnt[a], 1.0f);
  const float ic = 1.0f / fmaxf(cnt[c], 1.0f);
  float feat[32];
#pragma unroll
  for (int k = 0; k < 16; ++k) feat[k] = gemb[a * 16 + k] * ia;
#pragma unroll
  for (int k = 0; k < 16; ++k) feat[16 + k] = gemb[c * 16 + k] * ic;
  float z1[16];
#pragma unroll
  for (int j = 0; j < 16; ++j) {
    float s = sb1[j];
#pragma unroll
    for (int k = 0; k < 32; ++k) s = fmaf(feat[k], sW1[k * 16 + j], s);
    z1[j] = fmaxf(s, 0.f);
  }
  float z2[8];
#pragma unroll
  for (int j = 0; j < 8; ++j) {
    float s = sb2[j];
#pragma unroll
    for (int k = 0; k < 16; ++k) s = fmaf(z1[k], sW2[k * 8 + j], s);
    z2[j] = fmaxf(s, 0.f);
  }
  float z3 = sb3;
#pragma unroll
  for (int k = 0; k < 8; ++k) z3 = fmaf(z2[k], sW3[k], z3);
  out[l] = 1.f / (1.f + expf(-z3));
}

}  // namespace

extern "C" void kernel_launch(void* const* d_in, const int* in_sizes, int n_in,
                              void* d_out, int out_size, void* d_ws, size_t ws_size,
                              hipStream_t stream) {
  (void)in_sizes; (void)n_in; (void)out_size; (void)ws_size;
  const float* x = (const float*)d_in[0];
  const int* src = (const int*)d_in[1];
  const int* dst = (const int*)d_in[2];
  const int* batch = (const int*)d_in[3];
  const int* link = (const int*)d_in[4];
  const float *Wl[4], *bl[4], *Wrl[4], *brl[4], *gl[4], *btl[4];
  for (int i = 0; i < 4; ++i) {
    Wl[i] = (const float*)d_in[5 + 6 * i + 0];
    bl[i] = (const float*)d_in[5 + 6 * i + 1];
    Wrl[i] = (const float*)d_in[5 + 6 * i + 2];
    brl[i] = (const float*)d_in[5 + 6 * i + 3];
    gl[i] = (const float*)d_in[5 + 6 * i + 4];
    btl[i] = (const float*)d_in[5 + 6 * i + 5];
  }
  const float* Wm1 = (const float*)d_in[29];
  const float* bm1 = (const float*)d_in[30];
  const float* Wm2 = (const float*)d_in[31];
  const float* bm2 = (const float*)d_in[32];
  const float* Wm3 = (const float*)d_in[33];
  const float* bm3 = (const float*)d_in[34];
  float* out = (float*)d_out;

  // workspace layout (4B units unless noted):
  char* wsb = (char*)d_ws;
  int* deg_i = (int*)wsb;                      // N
  int* row_ptr = deg_i + N;                    // N+1
  int* cursor = row_ptr + (N + 1);             // N
  float* dis = (float*)(cursor + N);           // N
  int* bsum = (int*)(dis + N);                 // NB
  int* boff = bsum + NB;                       // NB
  int* col = boff + NB;                        // E
  unsigned short* hdb = (unsigned short*)(col + E);  // N*64 bf16
  float* bufB = (float*)(hdb + (size_t)N * 64);      // N*64 (r)
  float* bufC = bufB + (size_t)N * 64;               // N*64 (layer io)
  float* gemb = bufC + (size_t)N * 64;               // G*16 (+cnt adjacent)
  float* cnt = gemb + (size_t)G * 16;                // G

  // ---- CSR build ----
  hipMemsetAsync(deg_i, 0, N * sizeof(int), stream);
  hist_part_kernel<<<2048, 256, 0, stream>>>(dst, deg_i);
  {
    void* args[] = {&deg_i, &bsum, &boff, &row_ptr, &cursor, &dis};
    hipLaunchCooperativeKernel((void*)scan_fused_kernel, dim3(NB), dim3(256), args, 0, stream);
  }
  fill_part_kernel<<<2048, 256, 0, stream>>>(src, dst, cursor, col);

  const int AGG_BLOCKS = 2048;

  // Layer 1: 128 -> 64
  gemm2_kernel<128, 64, false><<<((N / 4) * 16 + 1023) / 1024, 1024, 0, stream>>>(
      x, Wl[0], Wrl[0], dis, hdb, bufB, nullptr);
  gcn_agg_kernel<64, false><<<AGG_BLOCKS, 256, 0, stream>>>(row_ptr, col, hdb, bufB, dis,
                                                            bl[0], brl[0], gl[0], btl[0], bufC,
                                                            batch, gemb, cnt);
  // Layer 2: 64 -> 32
  gemm2_kernel<64, 32, false><<<((N / 4) * 8 + 1023) / 1024, 1024, 0, stream>>>(
      bufC, Wl[1], Wrl[1], dis, hdb, bufB, nullptr);
  gcn_agg_kernel<32, false><<<AGG_BLOCKS, 256, 0, stream>>>(row_ptr, col, hdb, bufB, dis,
                                                            bl[1], brl[1], gl[1], btl[1], bufC,
                                                            batch, gemb, cnt);
  // Layer 3: 32 -> 16
  gemm2_kernel<32, 16, false><<<((N / 4) * 4 + 1023) / 1024, 1024, 0, stream>>>(
      bufC, Wl[2], Wrl[2], dis, hdb, bufB, nullptr);
  gcn_agg_kernel<16, false><<<AGG_BLOCKS, 256, 0, stream>>>(row_ptr, col, hdb, bufB, dis,
                                                            bl[2], brl[2], gl[2], btl[2], bufC,
                                                            batch, gemb, cnt);
  // Layer 4: 16 -> 16 (gemb/cnt zeroing folded into the GEMM; pool fused into agg)
  gemm2_kernel<16, 16, true><<<((N / 4) * 4 + 1023) / 1024, 1024, 0, stream>>>(
      bufC, Wl[3], Wrl[3], dis, hdb, bufB, gemb);
  gcn_agg_kernel<16, true><<<AGG_BLOCKS, 256, 0, stream>>>(row_ptr, col, hdb, bufB, dis,
                                                           bl[3], brl[3], gl[3], btl[3], nullptr,
                                                           batch, gemb, cnt);
  // link MLP (pool-normalize folded in)
  mlp_kernel<<<(L + 255) / 256, 256, 0, stream>>>(gemb, cnt, link, Wm1, bm1, Wm2, bm2, Wm3, bm3,
                                                  out);
}